// Round 5
// baseline (202004.529 us; speedup 1.0000x reference)
//
#include <hip/hip_runtime.h>
#include <hip/hip_cooperative_groups.h>
#include <math.h>

namespace cg = cooperative_groups;

// Problem dims (fixed by the reference)
#define T_DIM   512
#define B_DIM   64
#define INP_DIM 512
#define HS_DIM  2048
#define OUT_DIM 512

// Persistent device-global scratch. All buffers fully rewritten every call.
static __device__ float g_dataT[(size_t)T_DIM * INP_DIM * B_DIM]; // [t][k][b]
static __device__ float g_prex[(size_t)T_DIM * HS_DIM * B_DIM];   // [t][j][b]
static __device__ float g_hT4[HS_DIM * B_DIM];                    // quad-packed [j/4][b][4]
static __device__ float g_rT4[HS_DIM * B_DIM];                    // quad-packed [j/4][b][4]
static __device__ float g_potT[HS_DIM * B_DIM];                   // linear [j][b] (fallback path only)

// async global->LDS, 16B per lane (wave writes lds_base + lane*16)
__device__ __forceinline__ void async_ld16(const float* g, float* l) {
    __builtin_amdgcn_global_load_lds(
        (const __attribute__((address_space(1))) void*)g,
        (__attribute__((address_space(3))) void*)l, 16, 0, 0);
}

__global__ __launch_bounds__(256) void zero_state_kernel() {
    int i = blockIdx.x * 256 + threadIdx.x;
    if (i < HS_DIM * B_DIM) { g_hT4[i] = 0.f; g_potT[i] = 0.f; }
}

// data [t][b][k] -> g_dataT [t][k][b]
__global__ __launch_bounds__(256) void transpose_data_kernel(const float* __restrict__ data) {
    __shared__ float tile[64][65];
    const int t = blockIdx.x;
    const float* src = data + (size_t)t * B_DIM * INP_DIM;
    float* dst = g_dataT + (size_t)t * INP_DIM * B_DIM;
    for (int kt = 0; kt < INP_DIM / 64; ++kt) {
        const int k0 = kt * 64;
        __syncthreads();
        for (int i = threadIdx.x; i < 64 * 64; i += 256) {
            int b = i >> 6, kk = i & 63;
            tile[b][kk] = src[b * INP_DIM + k0 + kk];
        }
        __syncthreads();
        for (int i = threadIdx.x; i < 64 * 64; i += 256) {
            int k = i >> 6, b2 = i & 63;
            dst[(size_t)(k0 + k) * B_DIM + b2] = tile[b2][k];
        }
    }
}

// g_prex[t][j][b] = bih[j] + bhh[j] + sum_k dataT[t][k][b] * Wih[j][k]
__global__ __launch_bounds__(256) void prex_kernel(const float* __restrict__ Wih,
                                                   const float* __restrict__ bih,
                                                   const float* __restrict__ bhh) {
    __shared__ float lds[128 * B_DIM];
    const int t = blockIdx.y;
    const int lane = threadIdx.x & 63;
    const int wv = __builtin_amdgcn_readfirstlane(threadIdx.x >> 6);
    const int j0 = blockIdx.x * 32 + wv * 8;
    const float* xT = g_dataT + (size_t)t * INP_DIM * B_DIM;
    float acc[8] = {};
    for (int k0 = 0; k0 < INP_DIM; k0 += 128) {
        __syncthreads();
        {
            const float4* s4 = (const float4*)(xT + (size_t)k0 * B_DIM);
            float4* d4 = (float4*)lds;
            for (int i = threadIdx.x; i < 128 * B_DIM / 4; i += 256) d4[i] = s4[i];
        }
        __syncthreads();
        for (int k = 0; k < 128; k += 4) {
            float w[8][4];
            #pragma unroll
            for (int c = 0; c < 8; ++c)
                #pragma unroll
                for (int u = 0; u < 4; ++u)
                    w[c][u] = Wih[(size_t)(j0 + c) * INP_DIM + k0 + k + u];
            #pragma unroll
            for (int u = 0; u < 4; ++u) {
                float hv = lds[(k + u) * B_DIM + lane];
                #pragma unroll
                for (int c = 0; c < 8; ++c) acc[c] += hv * w[c][u];
            }
        }
    }
    #pragma unroll
    for (int c = 0; c < 8; ++c) {
        int j = j0 + c;
        g_prex[((size_t)t * HS_DIM + j) * B_DIM + lane] = acc[c] + bih[j] + bhh[j];
    }
}

// Wave computes its K-eighth (64 k4) of 8 output columns from LDS-resident weights.
// srcT4 quad-packed [k4][64][4] in global; wl = LDS weight slice [8][2048] row-major.
// Register double-buffered global loads (static indexing only).
__device__ __forceinline__ void eighth_gemm(float acc[8], const float* __restrict__ srcT4,
                                            const float* __restrict__ wl,
                                            int kq4, int lane) {
    const float4* gp = (const float4*)srcT4 + (size_t)kq4 * 64 + lane;
    float4 bufA[8], bufB[8];
    #pragma unroll
    for (int r = 0; r < 8; ++r) bufA[r] = gp[r * 64];
    #pragma unroll 1
    for (int ch = 0; ch < 8; ch += 2) {
        #pragma unroll
        for (int r = 0; r < 8; ++r) bufB[r] = gp[((ch + 1) * 8 + r) * 64];
        #pragma unroll
        for (int r = 0; r < 8; ++r) {
            const float4 h4 = bufA[r];
            const int k = (kq4 + ch * 8 + r) * 4;
            #pragma unroll
            for (int c = 0; c < 8; ++c) {
                const float4 w = *(const float4*)&wl[c * HS_DIM + k];
                acc[c] = fmaf(h4.x, w.x, acc[c]);
                acc[c] = fmaf(h4.y, w.y, acc[c]);
                acc[c] = fmaf(h4.z, w.z, acc[c]);
                acc[c] = fmaf(h4.w, w.w, acc[c]);
            }
        }
        if (ch + 2 < 8) {
            #pragma unroll
            for (int r = 0; r < 8; ++r) bufA[r] = gp[((ch + 2) * 8 + r) * 64];
        }
        #pragma unroll
        for (int r = 0; r < 8; ++r) {
            const float4 h4 = bufB[r];
            const int k = (kq4 + (ch + 1) * 8 + r) * 4;
            #pragma unroll
            for (int c = 0; c < 8; ++c) {
                const float4 w = *(const float4*)&wl[c * HS_DIM + k];
                acc[c] = fmaf(h4.x, w.x, acc[c]);
                acc[c] = fmaf(h4.y, w.y, acc[c]);
                acc[c] = fmaf(h4.z, w.z, acc[c]);
                acc[c] = fmaf(h4.w, w.w, acc[c]);
            }
        }
    }
}

// Persistent cooperative kernel: all 512 recurrent steps.
// 256 blocks (1/CU) x 512 threads (8 waves = 2/SIMD). Block owns 8 output cols;
// weight slices (Whh, Wp: 64 KB each) live in STATIC LDS for the whole kernel.
// Wave wv = output col j0+wv AND k-eighth [wv*256, wv*256+256). pot in registers.
__global__ __launch_bounds__(512, 1) void rnn_persistent(const float* __restrict__ Whh,
                                                         const float* __restrict__ Wp,
                                                         const float* __restrict__ bp,
                                                         const float* __restrict__ decay) {
    __shared__ float w_hh[8 * HS_DIM];   // 64 KB
    __shared__ float w_p[8 * HS_DIM];    // 64 KB
    __shared__ float red[8 * 8 * 64];    // 16 KB [wave][col][b]

    const int j0 = blockIdx.x * 8;
    const int lane = threadIdx.x & 63;
    const int wv = threadIdx.x >> 6;   // 0..7
    const int kq4 = wv * 64;           // wave's k4 range [kq4, kq4+64)

    // one-time weight preload into LDS
    {
        const float4* A = (const float4*)(Whh + (size_t)j0 * HS_DIM);
        const float4* B = (const float4*)(Wp + (size_t)j0 * HS_DIM);
        float4* a = (float4*)w_hh;
        float4* b = (float4*)w_p;
        for (int i = threadIdx.x; i < 8 * HS_DIM / 4; i += 512) { a[i] = A[i]; b[i] = B[i]; }
    }
    // thread owns output element (col jj = j0+wv, batch lane) in the epilogue
    const int jj = j0 + wv;
    const float bpv = bp[jj];
    const float dev = decay[jj];
    const size_t rt4_idx = (size_t)(jj >> 2) * 256 + lane * 4 + (jj & 3);
    float pot = 0.f;
    __syncthreads();

    cg::grid_group grid = cg::this_grid();

    for (int t = 0; t < T_DIM; ++t) {
        // ---------- Phase A: r = tanh(prex[t] + h @ Whh^T) ----------
        {
            float acc[8] = {};
            eighth_gemm(acc, g_hT4, w_hh, kq4, lane);
            #pragma unroll
            for (int c = 0; c < 8; ++c) red[(wv * 8 + c) * 64 + lane] = acc[c];
            __syncthreads();
            float s = 0.f;
            #pragma unroll
            for (int w = 0; w < 8; ++w) s += red[(w * 8 + wv) * 64 + lane];
            float rr = tanhf(g_prex[((size_t)t * HS_DIM + jj) * B_DIM + lane] + s);
            g_rT4[rt4_idx] = rr;
        }
        __threadfence();
        grid.sync();
        __threadfence();
        // ---------- Phase B: p = pot + r @ Wp^T + bp; h = relu(p); pot = min(p,0)*decay ----------
        {
            float acc[8] = {};
            eighth_gemm(acc, g_rT4, w_p, kq4, lane);
            #pragma unroll
            for (int c = 0; c < 8; ++c) red[(wv * 8 + c) * 64 + lane] = acc[c];
            __syncthreads();
            float s = 0.f;
            #pragma unroll
            for (int w = 0; w < 8; ++w) s += red[(w * 8 + wv) * 64 + lane];
            float p = pot + s + bpv;
            g_hT4[rt4_idx] = fmaxf(p, 0.f);
            pot = fminf(p, 0.f) * dev;
        }
        __threadfence();
        grid.sync();
        __threadfence();
    }
}

// ---------- Fallback path (round-3 proven step kernels, used only if coop launch fails) ----------
template <int PHASE>
__global__ __launch_bounds__(256) void step_kernel(const float* __restrict__ W,
                                                   const float* __restrict__ bp,
                                                   const float* __restrict__ decay,
                                                   int t) {
    __shared__ float lds[16384 + 2048];
    const int lane = threadIdx.x & 63;
    const int wv = __builtin_amdgcn_readfirstlane(threadIdx.x >> 6);
    const int j0 = blockIdx.x * 8;
    const float* src = (PHASE == 0) ? g_hT4 : g_rT4;
    const int kbase4 = wv * 128;
    float* myl = &lds[wv * 4096];

    float acc[8] = {};
    #pragma unroll
    for (int r = 0; r < 8; ++r)
        async_ld16(src + (size_t)(kbase4 + r) * 256 + lane * 4, myl + r * 256);

    for (int ch = 0; ch < 16; ++ch) {
        asm volatile("s_waitcnt vmcnt(0)" ::: "memory");
        if (ch < 15) {
            float* nl = myl + (((ch + 1) & 1) << 11);
            #pragma unroll
            for (int r = 0; r < 8; ++r)
                async_ld16(src + (size_t)(kbase4 + (ch + 1) * 8 + r) * 256 + lane * 4,
                           nl + r * 256);
        }
        const float* cl = myl + ((ch & 1) << 11);
        const float* Wk = W + (size_t)j0 * HS_DIM + (size_t)(kbase4 + ch * 8) * 4;
        #pragma unroll
        for (int r = 0; r < 8; ++r) {
            float4 h4 = *(const float4*)(cl + r * 256 + lane * 4);
            #pragma unroll
            for (int c = 0; c < 8; ++c) {
                const float* w = Wk + (size_t)c * HS_DIM + r * 4;
                acc[c] = fmaf(h4.x, w[0], acc[c]);
                acc[c] = fmaf(h4.y, w[1], acc[c]);
                acc[c] = fmaf(h4.z, w[2], acc[c]);
                acc[c] = fmaf(h4.w, w[3], acc[c]);
            }
        }
    }

    float* red = &lds[16384];
    #pragma unroll
    for (int c = 0; c < 8; ++c) red[(wv * 8 + c) * 64 + lane] = acc[c];
    __syncthreads();

    #pragma unroll
    for (int s = 0; s < 2; ++s) {
        int idx = threadIdx.x + s * 256;
        int c = idx >> 6, b = idx & 63;
        int j = j0 + c;
        float sum = red[(0 * 8 + c) * 64 + b] + red[(1 * 8 + c) * 64 + b] +
                    red[(2 * 8 + c) * 64 + b] + red[(3 * 8 + c) * 64 + b];
        if (PHASE == 0) {
            float rr = tanhf(g_prex[((size_t)t * HS_DIM + j) * B_DIM + b] + sum);
            g_rT4[(size_t)(j >> 2) * 256 + b * 4 + (j & 3)] = rr;
        } else {
            float p = g_potT[(size_t)j * B_DIM + b] + sum + bp[j];
            g_hT4[(size_t)(j >> 2) * 256 + b * 4 + (j & 3)] = fmaxf(p, 0.f);
            g_potT[(size_t)j * B_DIM + b] = fminf(p, 0.f) * decay[j];
        }
    }
}

// out[b][o] = bout[o] + sum_j h[j][b] * Wout[o][j]
__global__ __launch_bounds__(256) void out_kernel(const float* __restrict__ Wout,
                                                  const float* __restrict__ bout,
                                                  float* __restrict__ out) {
    const int lane = threadIdx.x & 63;
    const int wv = __builtin_amdgcn_readfirstlane(threadIdx.x >> 6);
    const int o0 = blockIdx.x * 16 + wv * 4;
    float acc[4] = {};
    for (int k4 = 0; k4 < HS_DIM / 4; ++k4) {
        float4 h4 = *(const float4*)&g_hT4[(size_t)k4 * 256 + lane * 4];
        #pragma unroll
        for (int c = 0; c < 4; ++c) {
            const float* w = Wout + (size_t)(o0 + c) * HS_DIM + (size_t)k4 * 4;
            acc[c] = fmaf(h4.x, w[0], acc[c]);
            acc[c] = fmaf(h4.y, w[1], acc[c]);
            acc[c] = fmaf(h4.z, w[2], acc[c]);
            acc[c] = fmaf(h4.w, w[3], acc[c]);
        }
    }
    #pragma unroll
    for (int c = 0; c < 4; ++c)
        out[(size_t)lane * OUT_DIM + o0 + c] = acc[c] + bout[o0 + c];
}

extern "C" void kernel_launch(void* const* d_in, const int* in_sizes, int n_in,
                              void* d_out, int out_size, void* d_ws, size_t ws_size,
                              hipStream_t stream) {
    const float* data  = (const float*)d_in[0];
    const float* Wih   = (const float*)d_in[1];
    const float* bih   = (const float*)d_in[2];
    const float* Whh   = (const float*)d_in[3];
    const float* bhh   = (const float*)d_in[4];
    const float* Wp    = (const float*)d_in[5];
    const float* bp    = (const float*)d_in[6];
    const float* decay = (const float*)d_in[7];
    const float* Wout  = (const float*)d_in[8];
    const float* bout  = (const float*)d_in[9];
    float* out = (float*)d_out;

    zero_state_kernel<<<(HS_DIM * B_DIM + 255) / 256, 256, 0, stream>>>();
    transpose_data_kernel<<<T_DIM, 256, 0, stream>>>(data);
    prex_kernel<<<dim3(HS_DIM / 32, T_DIM), 256, 0, stream>>>(Wih, bih, bhh);

    void* kargs[] = {(void*)&Whh, (void*)&Wp, (void*)&bp, (void*)&decay};
    hipError_t ce = hipLaunchCooperativeKernel((void*)rnn_persistent, dim3(256), dim3(512),
                                               kargs, 0, stream);
    if (ce != hipSuccess) {
        // Fallback: proven per-step kernels (slower but correct).
        for (int t = 0; t < T_DIM; ++t) {
            step_kernel<0><<<HS_DIM / 8, 256, 0, stream>>>(Whh, bp, decay, t);
            step_kernel<1><<<HS_DIM / 8, 256, 0, stream>>>(Wp, bp, decay, t);
        }
    }

    out_kernel<<<OUT_DIM / 16, 256, 0, stream>>>(Wout, bout, out);
}

// Round 6
// 133088.171 us; speedup vs baseline: 1.5178x; 1.5178x over previous
//
#include <hip/hip_runtime.h>
#include <math.h>

// Problem dims (fixed by the reference)
#define T_DIM   512
#define B_DIM   64
#define INP_DIM 512
#define HS_DIM  2048
#define OUT_DIM 512

// Persistent device-global scratch. All buffers fully rewritten every call.
static __device__ float g_dataT[(size_t)T_DIM * INP_DIM * B_DIM]; // [t][k][b]
static __device__ float g_prex[(size_t)T_DIM * HS_DIM * B_DIM];   // [t][j][b]
static __device__ float g_hT4[HS_DIM * B_DIM];                    // quad-packed [j/4][b][4]
static __device__ float g_rT4[HS_DIM * B_DIM];                    // quad-packed [j/4][b][4]
static __device__ unsigned g_bar;                                 // global barrier counter

__global__ __launch_bounds__(256) void zero_state_kernel() {
    int i = blockIdx.x * 256 + threadIdx.x;
    if (i < HS_DIM * B_DIM) g_hT4[i] = 0.f;
    if (i == 0) g_bar = 0u;
}

// data [t][b][k] -> g_dataT [t][k][b]
__global__ __launch_bounds__(256) void transpose_data_kernel(const float* __restrict__ data) {
    __shared__ float tile[64][65];
    const int t = blockIdx.x;
    const float* src = data + (size_t)t * B_DIM * INP_DIM;
    float* dst = g_dataT + (size_t)t * INP_DIM * B_DIM;
    for (int kt = 0; kt < INP_DIM / 64; ++kt) {
        const int k0 = kt * 64;
        __syncthreads();
        for (int i = threadIdx.x; i < 64 * 64; i += 256) {
            int b = i >> 6, kk = i & 63;
            tile[b][kk] = src[b * INP_DIM + k0 + kk];
        }
        __syncthreads();
        for (int i = threadIdx.x; i < 64 * 64; i += 256) {
            int k = i >> 6, b2 = i & 63;
            dst[(size_t)(k0 + k) * B_DIM + b2] = tile[b2][k];
        }
    }
}

// g_prex[t][j][b] = bih[j] + bhh[j] + sum_k dataT[t][k][b] * Wih[j][k]
__global__ __launch_bounds__(256) void prex_kernel(const float* __restrict__ Wih,
                                                   const float* __restrict__ bih,
                                                   const float* __restrict__ bhh) {
    __shared__ float lds[128 * B_DIM];
    const int t = blockIdx.y;
    const int lane = threadIdx.x & 63;
    const int wv = __builtin_amdgcn_readfirstlane(threadIdx.x >> 6);
    const int j0 = blockIdx.x * 32 + wv * 8;
    const float* xT = g_dataT + (size_t)t * INP_DIM * B_DIM;
    float acc[8] = {};
    for (int k0 = 0; k0 < INP_DIM; k0 += 128) {
        __syncthreads();
        {
            const float4* s4 = (const float4*)(xT + (size_t)k0 * B_DIM);
            float4* d4 = (float4*)lds;
            for (int i = threadIdx.x; i < 128 * B_DIM / 4; i += 256) d4[i] = s4[i];
        }
        __syncthreads();
        for (int k = 0; k < 128; k += 4) {
            float w[8][4];
            #pragma unroll
            for (int c = 0; c < 8; ++c)
                #pragma unroll
                for (int u = 0; u < 4; ++u)
                    w[c][u] = Wih[(size_t)(j0 + c) * INP_DIM + k0 + k + u];
            #pragma unroll
            for (int u = 0; u < 4; ++u) {
                float hv = lds[(k + u) * B_DIM + lane];
                #pragma unroll
                for (int c = 0; c < 8; ++c) acc[c] += hv * w[c][u];
            }
        }
    }
    #pragma unroll
    for (int c = 0; c < 8; ++c) {
        int j = j0 + c;
        g_prex[((size_t)t * HS_DIM + j) * B_DIM + lane] = acc[c] + bih[j] + bhh[j];
    }
}

#define LD_ST8(dst, base, ro)                                                              \
    {                                                                                      \
        _Pragma("unroll") for (int r = 0; r < 8; ++r) {                                    \
            dst[2 * r] = __hip_atomic_load(base + (size_t)((ro) + r) * 128,                \
                                           __ATOMIC_RELAXED, __HIP_MEMORY_SCOPE_AGENT);    \
            dst[2 * r + 1] = __hip_atomic_load(base + (size_t)((ro) + r) * 128 + 1,        \
                                               __ATOMIC_RELAXED, __HIP_MEMORY_SCOPE_AGENT);\
        }                                                                                  \
    }

// Wave computes its K-eighth (64 k4) of 8 output columns from LDS-resident weights.
// State read via agent-scope (sc1) relaxed atomic 8B loads — coherent across XCDs
// WITHOUT any L2 invalidation. Register double-buffered, static indexing only.
__device__ __forceinline__ void eighth_gemm(float acc[8], const float* __restrict__ srcT4,
                                            const float* __restrict__ wl,
                                            int kq4, int lane) {
    const unsigned long long* gp =
        (const unsigned long long*)srcT4 + (((size_t)kq4 * 64 + lane) << 1);
    unsigned long long bufA[16], bufB[16];
    LD_ST8(bufA, gp, 0);
    #pragma unroll 1
    for (int ch = 0; ch < 8; ch += 2) {
        LD_ST8(bufB, gp, (ch + 1) * 8);
        #pragma unroll
        for (int r = 0; r < 8; ++r) {
            const float2 hlo = __builtin_bit_cast(float2, bufA[2 * r]);
            const float2 hhi = __builtin_bit_cast(float2, bufA[2 * r + 1]);
            const int k = (kq4 + ch * 8 + r) * 4;
            #pragma unroll
            for (int c = 0; c < 8; ++c) {
                const float4 w = *(const float4*)&wl[c * HS_DIM + k];
                acc[c] = fmaf(hlo.x, w.x, acc[c]);
                acc[c] = fmaf(hlo.y, w.y, acc[c]);
                acc[c] = fmaf(hhi.x, w.z, acc[c]);
                acc[c] = fmaf(hhi.y, w.w, acc[c]);
            }
        }
        if (ch + 2 < 8) LD_ST8(bufA, gp, (ch + 2) * 8);
        #pragma unroll
        for (int r = 0; r < 8; ++r) {
            const float2 hlo = __builtin_bit_cast(float2, bufB[2 * r]);
            const float2 hhi = __builtin_bit_cast(float2, bufB[2 * r + 1]);
            const int k = (kq4 + (ch + 1) * 8 + r) * 4;
            #pragma unroll
            for (int c = 0; c < 8; ++c) {
                const float4 w = *(const float4*)&wl[c * HS_DIM + k];
                acc[c] = fmaf(hlo.x, w.x, acc[c]);
                acc[c] = fmaf(hlo.y, w.y, acc[c]);
                acc[c] = fmaf(hhi.x, w.z, acc[c]);
                acc[c] = fmaf(hhi.y, w.w, acc[c]);
            }
        }
    }
}

// Global barrier with NO cache fences: sc1 stores are already at the coherence
// point once vmcnt==0, so arrival only needs one agent-scope atomicAdd per block.
__device__ __forceinline__ void gbar(unsigned target) {
    asm volatile("s_waitcnt vmcnt(0)" ::: "memory"); // my sc1 stores are globally visible
    __syncthreads();
    if (threadIdx.x == 0) {
        __hip_atomic_fetch_add(&g_bar, 1u, __ATOMIC_RELAXED, __HIP_MEMORY_SCOPE_AGENT);
        while (__hip_atomic_load(&g_bar, __ATOMIC_RELAXED, __HIP_MEMORY_SCOPE_AGENT) < target)
            __builtin_amdgcn_s_sleep(2);
    }
    __syncthreads();
}

// Persistent kernel: all 512 recurrent steps. 256 blocks (1/CU) x 512 threads
// (8 waves = 2/SIMD). Block owns 8 output cols; weight slices (64 KB each) in
// static LDS for the whole kernel. Wave wv = output col j0+wv AND k-eighth.
// pot in registers. Cross-block state strictly via sc1 (agent) accesses.
__global__ __launch_bounds__(512, 1) void rnn_persistent(const float* __restrict__ Whh,
                                                         const float* __restrict__ Wp,
                                                         const float* __restrict__ bp,
                                                         const float* __restrict__ decay) {
    __shared__ float w_hh[8 * HS_DIM];   // 64 KB
    __shared__ float w_p[8 * HS_DIM];    // 64 KB
    __shared__ float red[8 * 8 * 64];    // 16 KB [wave][col][b]

    const int j0 = blockIdx.x * 8;
    const int lane = threadIdx.x & 63;
    const int wv = threadIdx.x >> 6;   // 0..7
    const int kq4 = wv * 64;           // wave's k4 range [kq4, kq4+64)

    // one-time weight preload into LDS (normal cached loads; never invalidated)
    {
        const float4* A = (const float4*)(Whh + (size_t)j0 * HS_DIM);
        const float4* B = (const float4*)(Wp + (size_t)j0 * HS_DIM);
        float4* a = (float4*)w_hh;
        float4* b = (float4*)w_p;
        for (int i = threadIdx.x; i < 8 * HS_DIM / 4; i += 512) { a[i] = A[i]; b[i] = B[i]; }
    }
    const int jj = j0 + wv;
    const float bpv = bp[jj];
    const float dev = decay[jj];
    const size_t st_idx = (size_t)(jj >> 2) * 256 + lane * 4 + (jj & 3);
    float pot = 0.f;
    unsigned nbar = 0;
    __syncthreads();

    for (int t = 0; t < T_DIM; ++t) {
        // ---------- Phase A: r = tanh(prex[t] + h @ Whh^T) ----------
        {
            float acc[8] = {};
            eighth_gemm(acc, g_hT4, w_hh, kq4, lane);
            #pragma unroll
            for (int c = 0; c < 8; ++c) red[(wv * 8 + c) * 64 + lane] = acc[c];
            __syncthreads();
            float s = 0.f;
            #pragma unroll
            for (int w = 0; w < 8; ++w) s += red[(w * 8 + wv) * 64 + lane];
            float rr = tanhf(g_prex[((size_t)t * HS_DIM + jj) * B_DIM + lane] + s);
            __hip_atomic_store(&g_rT4[st_idx], rr, __ATOMIC_RELAXED, __HIP_MEMORY_SCOPE_AGENT);
            __syncthreads(); // red reuse safety
        }
        gbar(++nbar * 256u);
        // ---------- Phase B: p = pot + r @ Wp^T + bp; h = relu(p); pot = min(p,0)*decay ----------
        {
            float acc[8] = {};
            eighth_gemm(acc, g_rT4, w_p, kq4, lane);
            #pragma unroll
            for (int c = 0; c < 8; ++c) red[(wv * 8 + c) * 64 + lane] = acc[c];
            __syncthreads();
            float s = 0.f;
            #pragma unroll
            for (int w = 0; w < 8; ++w) s += red[(w * 8 + wv) * 64 + lane];
            float p = pot + s + bpv;
            __hip_atomic_store(&g_hT4[st_idx], fmaxf(p, 0.f), __ATOMIC_RELAXED, __HIP_MEMORY_SCOPE_AGENT);
            pot = fminf(p, 0.f) * dev;
            __syncthreads(); // red reuse safety
        }
        gbar(++nbar * 256u);
    }
}

// out[b][o] = bout[o] + sum_j h[j][b] * Wout[o][j]
// (fresh kernel launch => agent acquire invalidates L2s; reads see the sc1 state)
__global__ __launch_bounds__(256) void out_kernel(const float* __restrict__ Wout,
                                                  const float* __restrict__ bout,
                                                  float* __restrict__ out) {
    const int lane = threadIdx.x & 63;
    const int wv = __builtin_amdgcn_readfirstlane(threadIdx.x >> 6);
    const int o0 = blockIdx.x * 16 + wv * 4;
    float acc[4] = {};
    for (int k4 = 0; k4 < HS_DIM / 4; ++k4) {
        float4 h4 = *(const float4*)&g_hT4[(size_t)k4 * 256 + lane * 4];
        #pragma unroll
        for (int c = 0; c < 4; ++c) {
            const float* w = Wout + (size_t)(o0 + c) * HS_DIM + (size_t)k4 * 4;
            acc[c] = fmaf(h4.x, w[0], acc[c]);
            acc[c] = fmaf(h4.y, w[1], acc[c]);
            acc[c] = fmaf(h4.z, w[2], acc[c]);
            acc[c] = fmaf(h4.w, w[3], acc[c]);
        }
    }
    #pragma unroll
    for (int c = 0; c < 4; ++c)
        out[(size_t)lane * OUT_DIM + o0 + c] = acc[c] + bout[o0 + c];
}

extern "C" void kernel_launch(void* const* d_in, const int* in_sizes, int n_in,
                              void* d_out, int out_size, void* d_ws, size_t ws_size,
                              hipStream_t stream) {
    const float* data  = (const float*)d_in[0];
    const float* Wih   = (const float*)d_in[1];
    const float* bih   = (const float*)d_in[2];
    const float* Whh   = (const float*)d_in[3];
    const float* bhh   = (const float*)d_in[4];
    const float* Wp    = (const float*)d_in[5];
    const float* bp    = (const float*)d_in[6];
    const float* decay = (const float*)d_in[7];
    const float* Wout  = (const float*)d_in[8];
    const float* bout  = (const float*)d_in[9];
    float* out = (float*)d_out;

    zero_state_kernel<<<(HS_DIM * B_DIM + 255) / 256, 256, 0, stream>>>();
    transpose_data_kernel<<<T_DIM, 256, 0, stream>>>(data);
    prex_kernel<<<dim3(HS_DIM / 32, T_DIM), 256, 0, stream>>>(Wih, bih, bhh);
    rnn_persistent<<<dim3(256), dim3(512), 0, stream>>>(Whh, Wp, bp, decay);
    out_kernel<<<OUT_DIM / 16, 256, 0, stream>>>(Wout, bout, out);
}

// Round 7
// 94651.990 us; speedup vs baseline: 2.1342x; 1.4061x over previous
//
#include <hip/hip_runtime.h>
#include <math.h>

// Problem dims (fixed by the reference)
#define T_DIM   512
#define B_DIM   64
#define INP_DIM 512
#define HS_DIM  2048
#define OUT_DIM 512
#define SLOT    (HS_DIM * B_DIM)   // 131072 floats = 512 KB per state slot

// Persistent device-global scratch. Everything read is rewritten every call.
static __device__ float g_dataT[(size_t)T_DIM * INP_DIM * B_DIM]; // [t][k][b]
static __device__ float g_prex[(size_t)T_DIM * HS_DIM * B_DIM];   // [t][j][b]
// State rings: one fresh 512 KB slot per phase -> consumer L2s can never hold
// a stale copy, so reads are plain cached loads (shared within each XCD's L2).
static __device__ float g_hring[(size_t)(T_DIM + 1) * SLOT];      // h before step t; [0]=zeros
static __device__ float g_rring[(size_t)T_DIM * SLOT];            // r of step t
// 2-level global barrier (monotonic counters, reset each call)
static __device__ unsigned g_sub[8 * 16];                         // 8 counters, 64B-spaced
static __device__ unsigned g_rel;

__global__ __launch_bounds__(256) void zero_state_kernel() {
    int i = blockIdx.x * 256 + threadIdx.x;
    if (i < SLOT) g_hring[i] = 0.f;
    if (i < 8) g_sub[i * 16] = 0u;
    if (i == 8) g_rel = 0u;
}

// data [t][b][k] -> g_dataT [t][k][b]
__global__ __launch_bounds__(256) void transpose_data_kernel(const float* __restrict__ data) {
    __shared__ float tile[64][65];
    const int t = blockIdx.x;
    const float* src = data + (size_t)t * B_DIM * INP_DIM;
    float* dst = g_dataT + (size_t)t * INP_DIM * B_DIM;
    for (int kt = 0; kt < INP_DIM / 64; ++kt) {
        const int k0 = kt * 64;
        __syncthreads();
        for (int i = threadIdx.x; i < 64 * 64; i += 256) {
            int b = i >> 6, kk = i & 63;
            tile[b][kk] = src[b * INP_DIM + k0 + kk];
        }
        __syncthreads();
        for (int i = threadIdx.x; i < 64 * 64; i += 256) {
            int k = i >> 6, b2 = i & 63;
            dst[(size_t)(k0 + k) * B_DIM + b2] = tile[b2][k];
        }
    }
}

// g_prex[t][j][b] = bih[j] + bhh[j] + sum_k dataT[t][k][b] * Wih[j][k]
__global__ __launch_bounds__(256) void prex_kernel(const float* __restrict__ Wih,
                                                   const float* __restrict__ bih,
                                                   const float* __restrict__ bhh) {
    __shared__ float lds[128 * B_DIM];
    const int t = blockIdx.y;
    const int lane = threadIdx.x & 63;
    const int wv = __builtin_amdgcn_readfirstlane(threadIdx.x >> 6);
    const int j0 = blockIdx.x * 32 + wv * 8;
    const float* xT = g_dataT + (size_t)t * INP_DIM * B_DIM;
    float acc[8] = {};
    for (int k0 = 0; k0 < INP_DIM; k0 += 128) {
        __syncthreads();
        {
            const float4* s4 = (const float4*)(xT + (size_t)k0 * B_DIM);
            float4* d4 = (float4*)lds;
            for (int i = threadIdx.x; i < 128 * B_DIM / 4; i += 256) d4[i] = s4[i];
        }
        __syncthreads();
        for (int k = 0; k < 128; k += 4) {
            float w[8][4];
            #pragma unroll
            for (int c = 0; c < 8; ++c)
                #pragma unroll
                for (int u = 0; u < 4; ++u)
                    w[c][u] = Wih[(size_t)(j0 + c) * INP_DIM + k0 + k + u];
            #pragma unroll
            for (int u = 0; u < 4; ++u) {
                float hv = lds[(k + u) * B_DIM + lane];
                #pragma unroll
                for (int c = 0; c < 8; ++c) acc[c] += hv * w[c][u];
            }
        }
    }
    #pragma unroll
    for (int c = 0; c < 8; ++c) {
        int j = j0 + c;
        g_prex[((size_t)t * HS_DIM + j) * B_DIM + lane] = acc[c] + bih[j] + bhh[j];
    }
}

// Wave computes its K-eighth (64 k4) of 8 output columns from LDS-resident weights.
// State read with PLAIN cached float4 loads (address is a fresh ring slot ->
// no staleness possible; 32 blocks/XCD share the L2 copy).
// Register double-buffered, static indexing only.
__device__ __forceinline__ void eighth_gemm(float acc[8], const float* __restrict__ srcT4,
                                            const float* __restrict__ wl,
                                            int kq4, int lane) {
    const float4* gp = (const float4*)srcT4 + (size_t)kq4 * 64 + lane;
    float4 bufA[8], bufB[8];
    #pragma unroll
    for (int r = 0; r < 8; ++r) bufA[r] = gp[r * 64];
    #pragma unroll 1
    for (int ch = 0; ch < 8; ch += 2) {
        #pragma unroll
        for (int r = 0; r < 8; ++r) bufB[r] = gp[((ch + 1) * 8 + r) * 64];
        #pragma unroll
        for (int r = 0; r < 8; ++r) {
            const float4 h4 = bufA[r];
            const int k = (kq4 + ch * 8 + r) * 4;
            #pragma unroll
            for (int c = 0; c < 8; ++c) {
                const float4 w = *(const float4*)&wl[c * HS_DIM + k];
                acc[c] = fmaf(h4.x, w.x, acc[c]);
                acc[c] = fmaf(h4.y, w.y, acc[c]);
                acc[c] = fmaf(h4.z, w.z, acc[c]);
                acc[c] = fmaf(h4.w, w.w, acc[c]);
            }
        }
        if (ch + 2 < 8) {
            #pragma unroll
            for (int r = 0; r < 8; ++r) bufA[r] = gp[((ch + 2) * 8 + r) * 64];
        }
        #pragma unroll
        for (int r = 0; r < 8; ++r) {
            const float4 h4 = bufB[r];
            const int k = (kq4 + (ch + 1) * 8 + r) * 4;
            #pragma unroll
            for (int c = 0; c < 8; ++c) {
                const float4 w = *(const float4*)&wl[c * HS_DIM + k];
                acc[c] = fmaf(h4.x, w.x, acc[c]);
                acc[c] = fmaf(h4.y, w.y, acc[c]);
                acc[c] = fmaf(h4.z, w.z, acc[c]);
                acc[c] = fmaf(h4.w, w.w, acc[c]);
            }
        }
    }
}

// 2-level global barrier, no cache maintenance: sc1 stores are at the coherence
// point once vmcnt==0; arrival = 1 sub-counter add (32/counter) + leader bumps
// central release; everyone polls central. Monotonic counts (nbar = phase#).
__device__ __forceinline__ void gbar(unsigned nbar) {
    asm volatile("s_waitcnt vmcnt(0)" ::: "memory"); // publish my sc1 stores
    __syncthreads();
    if (threadIdx.x == 0) {
        unsigned v = __hip_atomic_fetch_add(&g_sub[(blockIdx.x & 7) * 16], 1u,
                                            __ATOMIC_RELAXED, __HIP_MEMORY_SCOPE_AGENT) + 1;
        if (v == nbar * 32u)
            __hip_atomic_fetch_add(&g_rel, 1u, __ATOMIC_RELAXED, __HIP_MEMORY_SCOPE_AGENT);
        while (__hip_atomic_load(&g_rel, __ATOMIC_RELAXED, __HIP_MEMORY_SCOPE_AGENT) < nbar * 8u)
            __builtin_amdgcn_s_sleep(8);
    }
    __syncthreads();
}

// Persistent kernel: all 512 recurrent steps. 256 blocks (1/CU) x 512 threads
// (8 waves = 2/SIMD). Block owns 8 output cols; weight slices (64 KB each) in
// static LDS. Wave wv = epilogue col j0+wv AND k-eighth. pot in registers.
// State writes: LDS-staged -> coalesced 16B/lane sc1 stores by waves 0-1.
__global__ __launch_bounds__(512, 1) void rnn_persistent(const float* __restrict__ Whh,
                                                         const float* __restrict__ Wp,
                                                         const float* __restrict__ bp,
                                                         const float* __restrict__ decay) {
    __shared__ float w_hh[8 * HS_DIM];   // 64 KB
    __shared__ float w_p[8 * HS_DIM];    // 64 KB
    __shared__ float red[8 * 8 * 64];    // 16 KB [wave][col][b]
    __shared__ float stage[8 * 64];      // 2 KB  [col][b]

    const int j0 = blockIdx.x * 8;
    const int lane = threadIdx.x & 63;
    const int wv = threadIdx.x >> 6;   // 0..7
    const int kq4 = wv * 64;           // wave's k4 range [kq4, kq4+64)

    // one-time weight preload into LDS (cached loads; L2 never invalidated here)
    {
        const float4* A = (const float4*)(Whh + (size_t)j0 * HS_DIM);
        const float4* B = (const float4*)(Wp + (size_t)j0 * HS_DIM);
        float4* a = (float4*)w_hh;
        float4* b = (float4*)w_p;
        for (int i = threadIdx.x; i < 8 * HS_DIM / 4; i += 512) { a[i] = A[i]; b[i] = B[i]; }
    }
    const int jj = j0 + wv;
    const float bpv = bp[jj];
    const float dev = decay[jj];
    float pot = 0.f;
    unsigned nbar = 0;
    __syncthreads();

    for (int t = 0; t < T_DIM; ++t) {
        // ---------- Phase A: r = tanh(prex[t] + h @ Whh^T) ----------
        {
            const float* hbuf = g_hring + (size_t)t * SLOT;
            float acc[8] = {};
            eighth_gemm(acc, hbuf, w_hh, kq4, lane);
            #pragma unroll
            for (int c = 0; c < 8; ++c) red[(wv * 8 + c) * 64 + lane] = acc[c];
            __syncthreads();
            float s = 0.f;
            #pragma unroll
            for (int w = 0; w < 8; ++w) s += red[(w * 8 + wv) * 64 + lane];
            stage[wv * 64 + lane] =
                tanhf(g_prex[((size_t)t * HS_DIM + jj) * B_DIM + lane] + s);
            __syncthreads();
            if (threadIdx.x < 128) { // waves 0-1: coalesced publish
                const int q = wv;
                float2 lo = make_float2(stage[(q * 4 + 0) * 64 + lane],
                                        stage[(q * 4 + 1) * 64 + lane]);
                float2 hi = make_float2(stage[(q * 4 + 2) * 64 + lane],
                                        stage[(q * 4 + 3) * 64 + lane]);
                unsigned long long* dst =
                    (unsigned long long*)(g_rring + (size_t)t * SLOT +
                                          ((size_t)(j0 >> 2) + q) * 256) + lane * 2;
                __hip_atomic_store(dst, __builtin_bit_cast(unsigned long long, lo),
                                   __ATOMIC_RELAXED, __HIP_MEMORY_SCOPE_AGENT);
                __hip_atomic_store(dst + 1, __builtin_bit_cast(unsigned long long, hi),
                                   __ATOMIC_RELAXED, __HIP_MEMORY_SCOPE_AGENT);
            }
        }
        gbar(++nbar);
        // ---------- Phase B: p = pot + r @ Wp^T + bp; h = relu(p); pot = min(p,0)*decay ----------
        {
            const float* rbuf = g_rring + (size_t)t * SLOT;
            float acc[8] = {};
            eighth_gemm(acc, rbuf, w_p, kq4, lane);
            #pragma unroll
            for (int c = 0; c < 8; ++c) red[(wv * 8 + c) * 64 + lane] = acc[c];
            __syncthreads();
            float s = 0.f;
            #pragma unroll
            for (int w = 0; w < 8; ++w) s += red[(w * 8 + wv) * 64 + lane];
            float p = pot + s + bpv;
            stage[wv * 64 + lane] = fmaxf(p, 0.f);
            pot = fminf(p, 0.f) * dev;
            __syncthreads();
            if (threadIdx.x < 128) {
                const int q = wv;
                float2 lo = make_float2(stage[(q * 4 + 0) * 64 + lane],
                                        stage[(q * 4 + 1) * 64 + lane]);
                float2 hi = make_float2(stage[(q * 4 + 2) * 64 + lane],
                                        stage[(q * 4 + 3) * 64 + lane]);
                unsigned long long* dst =
                    (unsigned long long*)(g_hring + (size_t)(t + 1) * SLOT +
                                          ((size_t)(j0 >> 2) + q) * 256) + lane * 2;
                __hip_atomic_store(dst, __builtin_bit_cast(unsigned long long, lo),
                                   __ATOMIC_RELAXED, __HIP_MEMORY_SCOPE_AGENT);
                __hip_atomic_store(dst + 1, __builtin_bit_cast(unsigned long long, hi),
                                   __ATOMIC_RELAXED, __HIP_MEMORY_SCOPE_AGENT);
            }
        }
        gbar(++nbar);
    }
}

// out[b][o] = bout[o] + sum_j h[j][b] * Wout[o][j]
// (fresh kernel launch => agent acquire; reads final ring slot)
__global__ __launch_bounds__(256) void out_kernel(const float* __restrict__ Wout,
                                                  const float* __restrict__ bout,
                                                  float* __restrict__ out) {
    const float* hT4 = g_hring + (size_t)T_DIM * SLOT;
    const int lane = threadIdx.x & 63;
    const int wv = __builtin_amdgcn_readfirstlane(threadIdx.x >> 6);
    const int o0 = blockIdx.x * 16 + wv * 4;
    float acc[4] = {};
    for (int k4 = 0; k4 < HS_DIM / 4; ++k4) {
        float4 h4 = *(const float4*)&hT4[(size_t)k4 * 256 + lane * 4];
        #pragma unroll
        for (int c = 0; c < 4; ++c) {
            const float* w = Wout + (size_t)(o0 + c) * HS_DIM + (size_t)k4 * 4;
            acc[c] = fmaf(h4.x, w[0], acc[c]);
            acc[c] = fmaf(h4.y, w[1], acc[c]);
            acc[c] = fmaf(h4.z, w[2], acc[c]);
            acc[c] = fmaf(h4.w, w[3], acc[c]);
        }
    }
    #pragma unroll
    for (int c = 0; c < 4; ++c)
        out[(size_t)lane * OUT_DIM + o0 + c] = acc[c] + bout[o0 + c];
}

extern "C" void kernel_launch(void* const* d_in, const int* in_sizes, int n_in,
                              void* d_out, int out_size, void* d_ws, size_t ws_size,
                              hipStream_t stream) {
    const float* data  = (const float*)d_in[0];
    const float* Wih   = (const float*)d_in[1];
    const float* bih   = (const float*)d_in[2];
    const float* Whh   = (const float*)d_in[3];
    const float* bhh   = (const float*)d_in[4];
    const float* Wp    = (const float*)d_in[5];
    const float* bp    = (const float*)d_in[6];
    const float* decay = (const float*)d_in[7];
    const float* Wout  = (const float*)d_in[8];
    const float* bout  = (const float*)d_in[9];
    float* out = (float*)d_out;

    zero_state_kernel<<<(SLOT + 255) / 256, 256, 0, stream>>>();
    transpose_data_kernel<<<T_DIM, 256, 0, stream>>>(data);
    prex_kernel<<<dim3(HS_DIM / 32, T_DIM), 256, 0, stream>>>(Wih, bih, bhh);
    rnn_persistent<<<dim3(256), dim3(512), 0, stream>>>(Whh, Wp, bp, decay);
    out_kernel<<<OUT_DIM / 16, 256, 0, stream>>>(Wout, bout, out);
}